// Round 1
// baseline (19.652 us; speedup 1.0000x reference)
//
#include <hip/hip_runtime.h>
#include <hip/hip_bf16.h>

// Co-attention collapses: softmax over a size-1 axis == 1.0 exactly, so
//   out[b, 0:10]  = sum_{l<12}  x1[b, l, :]
//   out[b, 10:20] = sum_{l<100} C [b, l, :]
// Pure memory-bound column-sum. B=16384, LC=100, LS=12, D=10.

#define BATCHES 16384
#define LC_DIM 100
#define LS_DIM 12
#define D_DIM 10

__global__ __launch_bounds__(256) void coattention_sum_kernel(
    const float* __restrict__ C,
    const float* __restrict__ x1,
    float* __restrict__ out)
{
    int t = blockIdx.x * blockDim.x + threadIdx.x;
    const int total = BATCHES * D_DIM;
    if (t >= total) return;

    int b = t / D_DIM;
    int d = t - b * D_DIM;

    // sum over LS=12 rows of x1[b, :, d]
    const float* xp = x1 + (size_t)b * (LS_DIM * D_DIM) + d;
    float ssum = 0.f;
#pragma unroll
    for (int l = 0; l < LS_DIM; ++l) ssum += xp[l * D_DIM];

    // sum over LC=100 rows of C[b, :, d]
    const float* cp = C + (size_t)b * (LC_DIM * D_DIM) + d;
    float csum = 0.f;
#pragma unroll 10
    for (int l = 0; l < LC_DIM; ++l) csum += cp[l * D_DIM];

    out[(size_t)b * 20 + d] = ssum;
    out[(size_t)b * 20 + 10 + d] = csum;
}

extern "C" void kernel_launch(void* const* d_in, const int* in_sizes, int n_in,
                              void* d_out, int out_size, void* d_ws, size_t ws_size,
                              hipStream_t stream) {
    const float* C  = (const float*)d_in[0];   // (B,100,10)
    const float* x1 = (const float*)d_in[1];   // (B,12,10)
    float* out = (float*)d_out;                // (B,1,20)

    const int total = BATCHES * D_DIM;         // 163840 threads
    const int block = 256;
    const int grid = (total + block - 1) / block;  // 640 blocks
    coattention_sum_kernel<<<grid, block, 0, stream>>>(C, x1, out);
}

// Round 2
// 18.348 us; speedup vs baseline: 1.0711x; 1.0711x over previous
//
#include <hip/hip_runtime.h>
#include <hip/hip_bf16.h>

// Co-attention collapses: softmax over a size-1 axis == 1.0 exactly, so
//   out[b, 0:10]  = sum_{l<12}  x1[b, l, :]
//   out[b, 10:20] = sum_{l<100} C [b, l, :]
// Pure memory-bound column-sum. B=16384, LC=100, LS=12, D=10.
//
// Layout trick: row stride = 10 floats = 5 float2. Thread owns a column
// PAIR (2p, 2p+1) -> aligned float2 loads, half the instructions of the
// scalar version. Each (b,p) unit is split across two wave-halves
// (lane 32 apart) with UNIFORM trip counts (no divergence):
//   half h sums C rows [50h, 50h+50) and x1 rows [6h, 6h+6).
// Partials combined with __shfl_xor(.,32); lanes<32 store.
// Grid: 81920 units / 32 per wave = 2560 one-wave blocks = 10 blocks/CU
// exactly (vs 640 blocks = 2.5/CU before -> tail imbalance).

#define BATCHES 16384

__global__ __launch_bounds__(64) void coattention_sum_kernel(
    const float* __restrict__ C,
    const float* __restrict__ x1,
    float* __restrict__ out)
{
    const int lane = threadIdx.x;            // 0..63
    const int half = lane >> 5;              // 0 or 1
    const int u = blockIdx.x * 32 + (lane & 31);   // unit id: (b, p), 0..81919
    const int b = u / 5;
    const int p = u - b * 5;                 // column-pair 0..4

    // float2 views: C batch = 500 float2 (100 rows x 5), x1 batch = 60 (12 x 5)
    const float2* __restrict__ cp =
        reinterpret_cast<const float2*>(C) + (size_t)b * 500 + half * 250 + p;
    const float2* __restrict__ xp =
        reinterpret_cast<const float2*>(x1) + (size_t)b * 60 + half * 30 + p;

    float sx = 0.f, sy = 0.f;
#pragma unroll
    for (int l = 0; l < 6; ++l) { float2 v = xp[l * 5]; sx += v.x; sy += v.y; }

    float cx = 0.f, cy = 0.f;
#pragma unroll
    for (int l = 0; l < 50; ++l) { float2 v = cp[l * 5]; cx += v.x; cy += v.y; }

    // combine the two halves (lane ^ 32 holds the other 50/6 rows)
    sx += __shfl_xor(sx, 32); sy += __shfl_xor(sy, 32);
    cx += __shfl_xor(cx, 32); cy += __shfl_xor(cy, 32);

    if (half == 0) {
        float2* o = reinterpret_cast<float2*>(out) + (size_t)b * 10;
        o[p]     = make_float2(sx, sy);   // sfinal cols 2p, 2p+1
        o[5 + p] = make_float2(cx, cy);   // cfinal cols 2p, 2p+1
    }
}

extern "C" void kernel_launch(void* const* d_in, const int* in_sizes, int n_in,
                              void* d_out, int out_size, void* d_ws, size_t ws_size,
                              hipStream_t stream) {
    const float* C  = (const float*)d_in[0];   // (B,100,10)
    const float* x1 = (const float*)d_in[1];   // (B,12,10)
    float* out = (float*)d_out;                // (B,1,20)

    const int units = BATCHES * 5;             // 81920 (b, column-pair)
    const int grid = units / 32;               // 2560 blocks, 64 thr (1 wave) each
    coattention_sum_kernel<<<grid, 64, 0, stream>>>(C, x1, out);
}

// Round 3
// 17.835 us; speedup vs baseline: 1.1019x; 1.0288x over previous
//
#include <hip/hip_runtime.h>
#include <hip/hip_bf16.h>

// Co-attention collapses: softmax over a size-1 axis == 1.0 exactly, so
//   out[b, 0:10]  = sum_{l<12}  x1[b, l, :]
//   out[b, 10:20] = sum_{l<100} C [b, l, :]
// Pure memory-bound column-sum. B=16384, LC=100, LS=12, D=10.
//
// R2 post-mortem: halving loads + perfect balance gained only 1.3 us ->
// latency-bound or overhead-bound, not instruction-bound. This round:
// 4-way row split per unit (25 C rows + 3 x1 rows per thread, 28 float2
// loads) + 2-step shfl_xor reduce, 20 waves/CU (2x R2's occupancy).
//
// Unit u = (b, p): batch b, column-pair p (row = 5 float2, p in 0..4).
// Wave: lane = q*16 + idx; 16 units/wave, quarter q sums C rows
// [25q,25q+25) and x1 rows [3q,3q+3). shfl_xor 16 then 32 combines.
// Block = 256 thr = 4 waves = 64 units. Grid = 81920/64 = 1280 = 5/CU.

#define BATCHES 16384

__global__ __launch_bounds__(256) void coattention_sum_kernel(
    const float* __restrict__ C,
    const float* __restrict__ x1,
    float* __restrict__ out)
{
    const int t = threadIdx.x;
    const int lane = t & 63;
    const int q = lane >> 4;                 // quarter 0..3
    const int wave = t >> 6;                 // 0..3
    const int u = blockIdx.x * 64 + wave * 16 + (lane & 15);
    const int b = u / 5;
    const int p = u - b * 5;                 // column-pair 0..4

    // float2 views: C batch = 500 float2 (100 rows x 5), x1 batch = 60 (12 x 5)
    const float2* __restrict__ cp =
        reinterpret_cast<const float2*>(C) + (size_t)b * 500 + q * 125 + p;
    const float2* __restrict__ xp =
        reinterpret_cast<const float2*>(x1) + (size_t)b * 60 + q * 15 + p;

    float sx = 0.f, sy = 0.f;
#pragma unroll
    for (int l = 0; l < 3; ++l)  { float2 v = xp[l * 5]; sx += v.x; sy += v.y; }

    float cx = 0.f, cy = 0.f;
#pragma unroll
    for (int l = 0; l < 25; ++l) { float2 v = cp[l * 5]; cx += v.x; cy += v.y; }

    // combine quarters: xor 16 (q0<->q1, q2<->q3), then xor 32
    sx += __shfl_xor(sx, 16); sy += __shfl_xor(sy, 16);
    cx += __shfl_xor(cx, 16); cy += __shfl_xor(cy, 16);
    sx += __shfl_xor(sx, 32); sy += __shfl_xor(sy, 32);
    cx += __shfl_xor(cx, 32); cy += __shfl_xor(cy, 32);

    if (q == 0) {
        float2* o = reinterpret_cast<float2*>(out) + (size_t)b * 10;
        o[p]     = make_float2(sx, sy);   // sfinal cols 2p, 2p+1
        o[5 + p] = make_float2(cx, cy);   // cfinal cols 2p, 2p+1
    }
}

extern "C" void kernel_launch(void* const* d_in, const int* in_sizes, int n_in,
                              void* d_out, int out_size, void* d_ws, size_t ws_size,
                              hipStream_t stream) {
    const float* C  = (const float*)d_in[0];   // (B,100,10)
    const float* x1 = (const float*)d_in[1];   // (B,12,10)
    float* out = (float*)d_out;                // (B,1,20)

    const int units = BATCHES * 5;             // 81920 (b, column-pair)
    const int grid = units / 64;               // 1280 blocks = 5/CU exactly
    coattention_sum_kernel<<<grid, 256, 0, stream>>>(C, x1, out);
}